// Round 1
// baseline (884.694 us; speedup 1.0000x reference)
//
#include <hip/hip_runtime.h>
#include <hip/hip_bf16.h>

// Shapes (fixed by the reference)
#define DIMD 1024
#define SEQL 4096
#define BATCH 4
#define NHEADS 16
#define DHEAD 64
#define KPROJ 64
#define MLPD 4096
#define NTOK (BATCH*SEQL)
#define EPSV 1e-5f

using short8 = __attribute__((ext_vector_type(8))) short;
using f32x4  = __attribute__((ext_vector_type(4))) float;

__device__ __forceinline__ float wave_reduce_sum(float v) {
    #pragma unroll
    for (int off = 32; off > 0; off >>= 1) v += __shfl_down(v, off, 64);
    return v;
}

// ---------- K1: per-token LN1 stats (mu, rstd) ----------
__global__ __launch_bounds__(256) void k_stats1(const float* __restrict__ x,
                                                float* __restrict__ stats) {
    int t = blockIdx.x;
    const float4 x4 = *(const float4*)(x + (size_t)t*DIMD + threadIdx.x*4);
    float s  = x4.x + x4.y + x4.z + x4.w;
    float ss = x4.x*x4.x + x4.y*x4.y + x4.z*x4.z + x4.w*x4.w;
    s = wave_reduce_sum(s); ss = wave_reduce_sum(ss);
    __shared__ float rs[4], rss[4];
    int wave = threadIdx.x >> 6, lane = threadIdx.x & 63;
    if (lane == 0) { rs[wave] = s; rss[wave] = ss; }
    __syncthreads();
    if (threadIdx.x == 0) {
        float S1 = rs[0]+rs[1]+rs[2]+rs[3];
        float S2 = rss[0]+rss[1]+rss[2]+rss[3];
        float mu = S1 * (1.0f/DIMD);
        float var = S2 * (1.0f/DIMD) - mu*mu;
        stats[2*t]   = mu;
        stats[2*t+1] = rsqrtf(var + EPSV);
    }
}

// ---------- K2: xnsum[b][d] = sum_s LN1(x)[b,s,d]  (64-token chunks, atomics) ----------
__global__ __launch_bounds__(256) void k_xnsum(const float* __restrict__ x,
                                               const float* __restrict__ stats,
                                               const float* __restrict__ g1,
                                               const float* __restrict__ be1,
                                               float* __restrict__ xnsum) {
    int b = blockIdx.x >> 6, sc = blockIdx.x & 63;
    int d = threadIdx.x * 4;
    int t0 = b*SEQL + sc*64;
    float a0=0,a1=0,a2=0,a3=0;
    for (int s = 0; s < 64; s++) {
        int t = t0 + s;
        float mu = stats[2*t], rstd = stats[2*t+1];
        const float4 x4 = *(const float4*)(x + (size_t)t*DIMD + d);
        a0 += (x4.x-mu)*rstd; a1 += (x4.y-mu)*rstd;
        a2 += (x4.z-mu)*rstd; a3 += (x4.w-mu)*rstd;
    }
    const float4 g4 = *(const float4*)(g1 + d);
    const float4 b4 = *(const float4*)(be1 + d);
    atomicAdd(&xnsum[b*DIMD + d + 0], a0*g4.x + 64.0f*b4.x);
    atomicAdd(&xnsum[b*DIMD + d + 1], a1*g4.y + 64.0f*b4.y);
    atomicAdd(&xnsum[b*DIMD + d + 2], a2*g4.z + 64.0f*b4.z);
    atomicAdd(&xnsum[b*DIMD + d + 3], a3*g4.w + 64.0f*b4.w);
}

// ---------- K3: Esum[k] = sum_n E[n,k]; Fsum likewise ----------
__global__ __launch_bounds__(256) void k_efsum(const float* __restrict__ E,
                                               const float* __restrict__ Fm,
                                               float* __restrict__ Esum,
                                               float* __restrict__ Fsum) {
    int g = blockIdx.x;                 // 16 blocks, 256-row slabs
    int k = threadIdx.x & 63, seg = threadIdx.x >> 6;
    __shared__ float red[4][64];
    int n0 = g*256 + seg*64;
    float pe = 0, pf = 0;
    for (int i = 0; i < 64; i++) {
        pe += E [(size_t)(n0+i)*KPROJ + k];
        pf += Fm[(size_t)(n0+i)*KPROJ + k];
    }
    red[seg][k] = pe; __syncthreads();
    if (seg == 0) atomicAdd(&Esum[k], red[0][k]+red[1][k]+red[2][k]+red[3][k]);
    __syncthreads();
    red[seg][k] = pf; __syncthreads();
    if (seg == 0) atomicAdd(&Fsum[k], red[0][k]+red[1][k]+red[2][k]+red[3][k]);
}

// ---------- K4: Ksum[b][:] = xnsum[b]@Wk ; Vsum[b][:] = xnsum[b]@Wv ----------
__global__ __launch_bounds__(256) void k_kvsum(const float* __restrict__ xnsum,
                                               const float* __restrict__ Wk,
                                               const float* __restrict__ Wv,
                                               float* __restrict__ Ksum,
                                               float* __restrict__ Vsum) {
    int i = blockIdx.x;                 // 32 blocks: b(2b) | which(1b) | jc(2b)
    int b = i >> 3, which = (i >> 2) & 1, jc = i & 3;
    const float* W = which ? Wv : Wk;
    float* outp = which ? Vsum : Ksum;
    int j = jc*256 + threadIdx.x;
    __shared__ float xs[DIMD];
    for (int d = threadIdx.x; d < DIMD; d += 256) xs[d] = xnsum[b*DIMD + d];
    __syncthreads();
    float acc = 0;
    #pragma unroll 8
    for (int d = 0; d < DIMD; d++) acc += xs[d] * W[(size_t)d*DIMD + j];
    outp[b*DIMD + j] = acc;
}

// ---------- K5a: Mt[b][h][d] = sum_j Wq[d][h*64+j]*Ksum[b][h*64+j] ----------
__global__ __launch_bounds__(256) void k_mt(const float* __restrict__ Wq,
                                            const float* __restrict__ Ksum,
                                            float* __restrict__ Mt) {
    int i = blockIdx.x;                 // 256 blocks: b(2b)|h(4b)|dc(2b)
    int dc = i & 3, h = (i >> 2) & 15, b = i >> 6;
    __shared__ float ks[DHEAD];
    if (threadIdx.x < DHEAD) ks[threadIdx.x] = Ksum[b*DIMD + h*DHEAD + threadIdx.x];
    __syncthreads();
    int d = dc*256 + threadIdx.x;
    float acc = 0;
    #pragma unroll 8
    for (int j = 0; j < DHEAD; j++) acc += Wq[(size_t)d*DIMD + h*DHEAD + j] * ks[j];
    Mt[((size_t)b*NHEADS + h)*DIMD + d] = acc;
}

// ---------- K5b: P[b][h][d] = sum_j Vsum[b][h*64+j]*Wo[h*64+j][d] ----------
__global__ __launch_bounds__(256) void k_p(const float* __restrict__ Wo,
                                           const float* __restrict__ Vsum,
                                           float* __restrict__ P) {
    int i = blockIdx.x;
    int dc = i & 3, h = (i >> 2) & 15, b = i >> 6;
    __shared__ float vs[DHEAD];
    if (threadIdx.x < DHEAD) vs[threadIdx.x] = Vsum[b*DIMD + h*DHEAD + threadIdx.x];
    __syncthreads();
    int d = dc*256 + threadIdx.x;
    float acc = 0;
    #pragma unroll 8
    for (int j = 0; j < DHEAD; j++) acc += vs[j] * Wo[(size_t)(h*DHEAD + j)*DIMD + d];
    P[((size_t)b*NHEADS + h)*DIMD + d] = acc;
}

// ---------- K6: per-token fused: LN1 -> qk -> softmax w -> y=x+sum_h w*P+bo -> LN2 -> bf16 xn2 ----------
__global__ __launch_bounds__(256) void k_attn_apply(
    const float* __restrict__ x, const float* __restrict__ stats,
    const float* __restrict__ Mt, const float* __restrict__ P,
    const float* __restrict__ Esum, const float* __restrict__ Fsum,
    const float* __restrict__ g1, const float* __restrict__ be1,
    const float* __restrict__ bo,
    const float* __restrict__ g2, const float* __restrict__ be2,
    float* __restrict__ y, __hip_bfloat16* __restrict__ xn2) {
    __shared__ float xn_s[DIMD];
    __shared__ float qk_s[NHEADS];
    __shared__ float w_s[NHEADS];
    __shared__ float red2[8];
    __shared__ float mu2_s, rs2_s;
    int t = blockIdx.x;
    int b = t >> 12;                    // SEQ = 4096
    int tid = threadIdx.x;
    int wave = tid >> 6, lane = tid & 63;
    float mu = stats[2*t], rstd = stats[2*t+1];
    int d4 = tid * 4;
    const float4 x4  = *(const float4*)(x + (size_t)t*DIMD + d4);
    const float4 g14 = *(const float4*)(g1 + d4);
    const float4 b14 = *(const float4*)(be1 + d4);
    float xnv0 = (x4.x-mu)*rstd*g14.x + b14.x;
    float xnv1 = (x4.y-mu)*rstd*g14.y + b14.y;
    float xnv2 = (x4.z-mu)*rstd*g14.z + b14.z;
    float xnv3 = (x4.w-mu)*rstd*g14.w + b14.w;
    xn_s[d4+0]=xnv0; xn_s[d4+1]=xnv1; xn_s[d4+2]=xnv2; xn_s[d4+3]=xnv3;
    __syncthreads();
    // qk[h] = xn . Mt[b][h][:]   (wave w handles heads 4w..4w+3)
    for (int hh = 0; hh < 4; hh++) {
        int h = wave*4 + hh;
        const float* Mh = Mt + ((size_t)b*NHEADS + h)*DIMD;
        float p = 0;
        #pragma unroll
        for (int i = 0; i < 16; i++) { int d = lane + i*64; p += xn_s[d]*Mh[d]; }
        p = wave_reduce_sum(p);
        if (lane == 0) qk_s[h] = p;
    }
    __syncthreads();
    // w[h] = sum_k softmax_k(scale*qk*Esum[k]) * Fsum[k]   (lane = k, 64 lanes)
    const float scale = 0.125f;         // DH^-0.5
    float ek = Esum[lane], fk = Fsum[lane];
    for (int hh = 0; hh < 4; hh++) {
        int h = wave*4 + hh;
        float c = qk_s[h] * scale;
        float logit = c * ek;
        float m = logit;
        #pragma unroll
        for (int off = 32; off > 0; off >>= 1) m = fmaxf(m, __shfl_down(m, off, 64));
        m = __shfl(m, 0, 64);
        float e = expf(logit - m);
        float s1 = e, s2 = e * fk;
        #pragma unroll
        for (int off = 32; off > 0; off >>= 1) {
            s1 += __shfl_down(s1, off, 64);
            s2 += __shfl_down(s2, off, 64);
        }
        if (lane == 0) w_s[h] = s2 / s1;
    }
    __syncthreads();
    // y = x + sum_h w[h]*P[b][h][:] + bo
    const float4 bo4 = *(const float4*)(bo + d4);
    float y0 = x4.x + bo4.x, y1 = x4.y + bo4.y, y2 = x4.z + bo4.z, y3 = x4.w + bo4.w;
    #pragma unroll
    for (int h = 0; h < NHEADS; h++) {
        float wv = w_s[h];
        const float4 p4 = *(const float4*)(P + ((size_t)b*NHEADS + h)*DIMD + d4);
        y0 += wv*p4.x; y1 += wv*p4.y; y2 += wv*p4.z; y3 += wv*p4.w;
    }
    float4 yo; yo.x = y0; yo.y = y1; yo.z = y2; yo.w = y3;
    *(float4*)(y + (size_t)t*DIMD + d4) = yo;
    // LN2 over y (in-block)
    float s  = y0+y1+y2+y3;
    float ss = y0*y0+y1*y1+y2*y2+y3*y3;
    s = wave_reduce_sum(s); ss = wave_reduce_sum(ss);
    if (lane == 0) { red2[wave] = s; red2[4+wave] = ss; }
    __syncthreads();
    if (tid == 0) {
        float S1 = red2[0]+red2[1]+red2[2]+red2[3];
        float S2 = red2[4]+red2[5]+red2[6]+red2[7];
        float m2 = S1*(1.0f/DIMD);
        float v2 = S2*(1.0f/DIMD) - m2*m2;
        mu2_s = m2; rs2_s = rsqrtf(v2 + EPSV);
    }
    __syncthreads();
    float mu2 = mu2_s, rs2 = rs2_s;
    const float4 g24 = *(const float4*)(g2 + d4);
    const float4 b24 = *(const float4*)(be2 + d4);
    union { __hip_bfloat16 h4[4]; uint2 v; } pk;
    pk.h4[0] = __float2bfloat16((y0-mu2)*rs2*g24.x + b24.x);
    pk.h4[1] = __float2bfloat16((y1-mu2)*rs2*g24.y + b24.y);
    pk.h4[2] = __float2bfloat16((y2-mu2)*rs2*g24.z + b24.z);
    pk.h4[3] = __float2bfloat16((y3-mu2)*rs2*g24.w + b24.w);
    *(uint2*)((char*)(xn2 + (size_t)t*DIMD + d4)) = pk.v;
}

// ---------- K7: transpose fp32 [R][C] -> bf16 [C][R] ----------
__global__ __launch_bounds__(256) void k_transpose_bf16(const float* __restrict__ src,
                                                        __hip_bfloat16* __restrict__ dst,
                                                        int R, int C) {
    __shared__ float tile[32][33];
    int c0 = blockIdx.x * 32, r0 = blockIdx.y * 32;
    int tx = threadIdx.x & 31, ty = threadIdx.x >> 5;   // ty: 0..7
    #pragma unroll
    for (int i = 0; i < 32; i += 8)
        tile[ty+i][tx] = src[(size_t)(r0+ty+i)*C + c0 + tx];
    __syncthreads();
    #pragma unroll
    for (int i = 0; i < 32; i += 8)
        dst[(size_t)(c0+ty+i)*R + r0 + tx] = __float2bfloat16(tile[tx][ty+i]);
}

// ---------- K8: bf16 GEMM C[M,N] = A[M,K] @ Bt[N,K]^T, 128x128 tile, mfma 16x16x32 ----------
// EPI==0: Cout = bf16, v = gelu(acc + bias)   (h = gelu(xn2@W1+b1))
// EPI==1: Cout = fp32, Cout += acc + bias     (out = y + h@W2 + b2)
template <int EPI>
__global__ __launch_bounds__(256) void k_gemm_bt(
    const __hip_bfloat16* __restrict__ A, const __hip_bfloat16* __restrict__ Bt,
    const float* __restrict__ bias, void* __restrict__ Cout,
    int M, int N, int K) {
    __shared__ __align__(16) unsigned short As[128*32];
    __shared__ __align__(16) unsigned short Bs[128*32];
    const int m0 = blockIdx.x * 128, n0 = blockIdx.y * 128;
    const int tid = threadIdx.x;
    const int wave = tid >> 6, lane = tid & 63;
    const int wm = (wave & 1) * 64, wn = (wave >> 1) * 64;
    const int quad = lane >> 4, l15 = lane & 15;
    f32x4 acc[4][4];
    #pragma unroll
    for (int i = 0; i < 4; i++)
        #pragma unroll
        for (int j = 0; j < 4; j++) acc[i][j] = 0;
    const int srow = tid >> 2, scol = (tid & 3) * 8;
    const unsigned short* Au = (const unsigned short*)A;
    const unsigned short* Bu = (const unsigned short*)Bt;
    for (int k0 = 0; k0 < K; k0 += 32) {
        uint4 a0 = *(const uint4*)(Au + (size_t)(m0+srow   )*K + k0 + scol);
        uint4 a1 = *(const uint4*)(Au + (size_t)(m0+srow+64)*K + k0 + scol);
        uint4 b0 = *(const uint4*)(Bu + (size_t)(n0+srow   )*K + k0 + scol);
        uint4 b1 = *(const uint4*)(Bu + (size_t)(n0+srow+64)*K + k0 + scol);
        __syncthreads();   // previous iter's ds_reads done before overwrite
        *(uint4*)&As[srow*32 + scol]      = a0;
        *(uint4*)&As[(srow+64)*32 + scol] = a1;
        *(uint4*)&Bs[srow*32 + scol]      = b0;
        *(uint4*)&Bs[(srow+64)*32 + scol] = b1;
        __syncthreads();
        short8 af[4], bf[4];
        #pragma unroll
        for (int mt = 0; mt < 4; mt++)
            af[mt] = *(const short8*)&As[(wm + mt*16 + l15)*32 + quad*8];
        #pragma unroll
        for (int nt = 0; nt < 4; nt++)
            bf[nt] = *(const short8*)&Bs[(wn + nt*16 + l15)*32 + quad*8];
        #pragma unroll
        for (int mt = 0; mt < 4; mt++)
            #pragma unroll
            for (int nt = 0; nt < 4; nt++)
                acc[mt][nt] = __builtin_amdgcn_mfma_f32_16x16x32_bf16(af[mt], bf[nt], acc[mt][nt], 0, 0, 0);
    }
    // epilogue: C/D layout row = quad*4 + r, col = l15
    #pragma unroll
    for (int nt = 0; nt < 4; nt++) {
        int col = n0 + wn + nt*16 + l15;
        float bv = bias[col];
        #pragma unroll
        for (int mt = 0; mt < 4; mt++) {
            #pragma unroll
            for (int r = 0; r < 4; r++) {
                int row = m0 + wm + mt*16 + quad*4 + r;
                float v = acc[mt][nt][r] + bv;
                if (EPI == 0) {
                    float gl = 0.5f * v * (1.0f + erff(v * 0.70710678118654752f));
                    ((__hip_bfloat16*)Cout)[(size_t)row*N + col] = __float2bfloat16(gl);
                } else {
                    ((float*)Cout)[(size_t)row*N + col] += v;
                }
            }
        }
    }
}

extern "C" void kernel_launch(void* const* d_in, const int* in_sizes, int n_in,
                              void* d_out, int out_size, void* d_ws, size_t ws_size,
                              hipStream_t stream) {
    const float* x   = (const float*)d_in[0];
    const float* Wq  = (const float*)d_in[1];
    const float* Wk  = (const float*)d_in[2];
    const float* Wv  = (const float*)d_in[3];
    const float* E   = (const float*)d_in[4];
    const float* Fm  = (const float*)d_in[5];
    const float* Wo  = (const float*)d_in[6];
    const float* bo  = (const float*)d_in[7];
    const float* g1  = (const float*)d_in[8];
    const float* be1 = (const float*)d_in[9];
    const float* g2  = (const float*)d_in[10];
    const float* be2 = (const float*)d_in[11];
    const float* W1  = (const float*)d_in[12];
    const float* bb1 = (const float*)d_in[13];
    const float* W2  = (const float*)d_in[14];
    const float* bb2 = (const float*)d_in[15];
    float* outp = (float*)d_out;

    char* ws = (char*)d_ws;
    size_t o = 0;
    auto alloc = [&](size_t bytes) -> char* {
        char* r = ws + o;
        o = (o + bytes + 255) & ~(size_t)255;
        return r;
    };
    float* xnsum = (float*)alloc((size_t)BATCH*DIMD*4);
    float* Esum  = (float*)alloc(KPROJ*4);
    float* Fsum  = (float*)alloc(KPROJ*4);
    float* stats = (float*)alloc((size_t)NTOK*2*4);
    float* Ksum  = (float*)alloc((size_t)BATCH*DIMD*4);
    float* Vsum  = (float*)alloc((size_t)BATCH*DIMD*4);
    float* Mt    = (float*)alloc((size_t)BATCH*NHEADS*DIMD*4);
    float* P     = (float*)alloc((size_t)BATCH*NHEADS*DIMD*4);
    __hip_bfloat16* xn2  = (__hip_bfloat16*)alloc((size_t)NTOK*DIMD*2);
    __hip_bfloat16* W1T  = (__hip_bfloat16*)alloc((size_t)DIMD*MLPD*2);
    __hip_bfloat16* W2T  = (__hip_bfloat16*)alloc((size_t)MLPD*DIMD*2);
    __hip_bfloat16* hbuf = (__hip_bfloat16*)alloc((size_t)NTOK*MLPD*2);

    hipMemsetAsync(xnsum, 0, (size_t)BATCH*DIMD*4, stream);
    hipMemsetAsync(Esum, 0, KPROJ*4, stream);
    hipMemsetAsync(Fsum, 0, KPROJ*4, stream);

    k_stats1<<<dim3(NTOK), dim3(256), 0, stream>>>(x, stats);
    k_xnsum<<<dim3(BATCH*64), dim3(256), 0, stream>>>(x, stats, g1, be1, xnsum);
    k_efsum<<<dim3(16), dim3(256), 0, stream>>>(E, Fm, Esum, Fsum);
    k_kvsum<<<dim3(32), dim3(256), 0, stream>>>(xnsum, Wk, Wv, Ksum, Vsum);
    k_mt<<<dim3(256), dim3(256), 0, stream>>>(Wq, Ksum, Mt);
    k_p<<<dim3(256), dim3(256), 0, stream>>>(Wo, Vsum, P);
    k_attn_apply<<<dim3(NTOK), dim3(256), 0, stream>>>(
        x, stats, Mt, P, Esum, Fsum, g1, be1, bo, g2, be2, outp, xn2);
    // W1: [K=1024][N=4096] -> W1T [4096][1024]; W2: [4096][1024] -> W2T [1024][4096]
    k_transpose_bf16<<<dim3(MLPD/32, DIMD/32), dim3(256), 0, stream>>>(W1, W1T, DIMD, MLPD);
    k_transpose_bf16<<<dim3(DIMD/32, MLPD/32), dim3(256), 0, stream>>>(W2, W2T, MLPD, DIMD);
    // GEMM1: h = gelu(xn2 @ W1 + b1)   M=16384 N=4096 K=1024
    k_gemm_bt<0><<<dim3(NTOK/128, MLPD/128), dim3(256), 0, stream>>>(
        xn2, W1T, bb1, (void*)hbuf, NTOK, MLPD, DIMD);
    // GEMM2: out = y + h @ W2 + b2     M=16384 N=1024 K=4096
    k_gemm_bt<1><<<dim3(NTOK/128, DIMD/128), dim3(256), 0, stream>>>(
        hbuf, W2T, bb2, (void*)outp, NTOK, DIMD, MLPD);
}